// Round 9
// baseline (191.717 us; speedup 1.0000x reference)
//
#include <hip/hip_runtime.h>
#include <math.h>

#define NUM_K 512
#define DIM   64
#define HW    4096
#define IMG   (DIM * HW)
#define OUT_Q 8388608
#define LOSS_OFF OUT_Q
#define IDX_OFF (OUT_Q + 1)
#define DELTA 8e-5f

// ws layout (bytes)
#define WS_EH   0        // bf16 hi codebook [512*64] = 64KB
#define WS_EL   65536    // bf16 lo codebook = 64KB
#define WS_SE   131072   // ||e||^2 f32 [512] = 2KB
#define WS_CNT  133120   // worklist counter
#define WS_PART 133376   // loss partials double[512] = 4KB
#define WS_ET   137472   // transposed codebook f32 [64][512] = 128KB
#define WS_WL   268544   // worklist pixel ids

typedef float f32x4 __attribute__((ext_vector_type(4)));
typedef short s8v   __attribute__((ext_vector_type(8)));

__device__ inline short f2bf(float f) {  // RNE f32->bf16
  unsigned u = __float_as_uint(f);
  return (short)((u + 0x7FFF + ((u >> 16) & 1)) >> 16);
}
__device__ inline float bf2f(short s) {
  return __uint_as_float(((unsigned)(unsigned short)s) << 16);
}

// K1: 8 blocks x 64 thr; LDS-staged coalesced reads; per-code sequential chains
__global__ void vq_prep(const float* __restrict__ emb, char* __restrict__ ws) {
  short* eh = (short*)(ws + WS_EH);
  short* el = (short*)(ws + WS_EL);
  float* se = (float*)(ws + WS_SE);
  float* et = (float*)(ws + WS_ET);
  __shared__ float ebuf[64][65];
  const int tid = threadIdx.x;        // 0..63
  const int kb  = blockIdx.x * 64;
  if (blockIdx.x == 0 && tid == 0) *(int*)(ws + WS_CNT) = 0;
#pragma unroll
  for (int i = 0; i < 64; ++i)        // coalesced: 64 consecutive floats/instr
    ebuf[i][tid] = emb[(size_t)(kb + i) * DIM + tid];
  __syncthreads();
  const int k = kb + tid;
  float s = 0.f;
#pragma unroll
  for (int j = 0; j < DIM; ++j) {     // j-ascending sequential (proven chain)
    const float v = ebuf[tid][j];     // pad 65 -> conflict-free row reads
    s = fmaf(v, v, s);
    const short h = f2bf(v);
    eh[k * DIM + j] = h;
    el[k * DIM + j] = f2bf(v - bf2f(h));
    et[j * NUM_K + k] = v;            // coalesced across tid
  }
  se[k] = s;
}

// K2: 512 thr / 8 waves; waves 0-3 codes 0-255, waves 4-7 codes 256-511;
// LDS min1/min2 merge; epilogue uses reconstructed x-hat (no x re-read).
__launch_bounds__(512, 4)
__global__ void vq_main(const float* __restrict__ in, const float* __restrict__ emb,
                        char* __restrict__ ws, float* __restrict__ out, int wlcap) {
  const short* eh = (const short*)(ws + WS_EH);
  const short* el = (const short*)(ws + WS_EL);
  const float* se = (const float*)(ws + WS_SE);
  int* wcnt  = (int*)(ws + WS_CNT);
  int* wlist = (int*)(ws + WS_WL);
  double* partial = (double*)(ws + WS_PART);
  __shared__ float m1s[2][256], m2s[2][256];
  __shared__ int   bkbuf[256];
  __shared__ double red[8];

  const int tid  = threadIdx.x;
  const int lane = tid & 63, w = tid >> 6;   // w 0..7
  const int side = w >> 2;                    // code half
  const int wq   = w & 3;                     // pixel quarter
  const int l15 = lane & 15, lh = lane >> 4;
  const int d0 = lh * 8;
  const int pblk = blockIdx.x * 256;
  const int n = pblk >> 12;                   // uniform (256 | 4096)
  const int hwb = pblk & 4095;
  const int p0 = wq * 64;

  // ---- A-fragments (both sides load; side 1 hits L1/L2) ----
  s8v ah[4][2], al[4][2];
#pragma unroll
  for (int rt = 0; rt < 4; ++rt) {
    const float* xp = in + (size_t)n * IMG + hwb + (p0 + rt * 16 + l15);
#pragma unroll
    for (int h = 0; h < 2; ++h) {
      s8v vh, vl;
#pragma unroll
      for (int j = 0; j < 8; ++j) {
        const float xv = xp[(h * 32 + d0 + j) * HW];
        const short hi = f2bf(xv);
        vh[j] = hi;
        vl[j] = f2bf(xv - bf2f(hi));
      }
      ah[rt][h] = vh; al[rt][h] = vl;
    }
  }

  // ---- 16 code-tiles for this side; packed (value|code) min1/min2 ----
  float m1[4][4], m2[4][4];
#pragma unroll
  for (int rt = 0; rt < 4; ++rt)
#pragma unroll
    for (int r = 0; r < 4; ++r) { m1[rt][r] = INFINITY; m2[rt][r] = INFINITY; }

  for (int ct = 0; ct < 16; ++ct) {
    const int c = side * 256 + ct * 16 + l15;  // this lane's code column
    const s8v beh0 = *(const s8v*)(eh + c * DIM + d0);
    const s8v beh1 = *(const s8v*)(eh + c * DIM + 32 + d0);
    const s8v bel0 = *(const s8v*)(el + c * DIM + d0);
    const s8v bel1 = *(const s8v*)(el + c * DIM + 32 + d0);
    const float sec = se[c];
#pragma unroll
    for (int rt = 0; rt < 4; ++rt) {
      f32x4 acc = {0.f, 0.f, 0.f, 0.f};
      acc = __builtin_amdgcn_mfma_f32_16x16x32_bf16(ah[rt][0], beh0, acc, 0, 0, 0);
      acc = __builtin_amdgcn_mfma_f32_16x16x32_bf16(ah[rt][1], beh1, acc, 0, 0, 0);
      acc = __builtin_amdgcn_mfma_f32_16x16x32_bf16(al[rt][0], beh0, acc, 0, 0, 0);
      acc = __builtin_amdgcn_mfma_f32_16x16x32_bf16(al[rt][1], beh1, acc, 0, 0, 0);
      acc = __builtin_amdgcn_mfma_f32_16x16x32_bf16(ah[rt][0], bel0, acc, 0, 0, 0);
      acc = __builtin_amdgcn_mfma_f32_16x16x32_bf16(ah[rt][1], bel1, acc, 0, 0, 0);
#pragma unroll
      for (int r = 0; r < 4; ++r) {
        const float cv = fmaf(-2.f, acc[r], sec);           // se - 2*dot
        const float pk = __int_as_float((__float_as_int(cv) & 0xFFFFFE00) | c);
        m2[rt][r] = fminf(m2[rt][r], fmaxf(m1[rt][r], pk));
        m1[rt][r] = fminf(m1[rt][r], pk);
      }
    }
  }

  // ---- reduce across 16 code-column lanes ----
#pragma unroll
  for (int s = 1; s < 16; s <<= 1) {
#pragma unroll
    for (int rt = 0; rt < 4; ++rt)
#pragma unroll
      for (int r = 0; r < 4; ++r) {
        const float o1 = __shfl_xor(m1[rt][r], s);
        const float o2 = __shfl_xor(m2[rt][r], s);
        const float hi = fmaxf(m1[rt][r], o1);
        m1[rt][r] = fminf(m1[rt][r], o1);
        m2[rt][r] = fminf(fminf(m2[rt][r], o2), hi);
      }
  }
  if (l15 == 0) {
#pragma unroll
    for (int rt = 0; rt < 4; ++rt)
#pragma unroll
      for (int r = 0; r < 4; ++r) {
        const int lp = p0 + rt * 16 + lh * 4 + r;           // C-row pixel
        m1s[side][lp] = m1[rt][r];
        m2s[side][lp] = m2[rt][r];
      }
  }
  __syncthreads();

  // ---- merge sides, write idx, flag + compaction (tid<256) ----
  if (tid < 256) {
    const float m1a = m1s[0][tid], m1b = m1s[1][tid];
    const float m2a = m2s[0][tid], m2b = m2s[1][tid];
    const float mm1 = fminf(m1a, m1b);
    // 2nd-smallest of union = min(m2a, m2b, larger-of-the-two-mins)
    const float mm2 = fminf(fminf(m2a, m2b), fmaxf(m1a, m1b));
    const int bk = __float_as_int(mm1) & 511;
    bkbuf[tid] = bk;
    out[IDX_OFF + pblk + tid] = (float)bk;                  // coalesced
    const int flagv = (mm2 - mm1 <= DELTA) ? 1 : 0;
    const unsigned long long b = __ballot(flagv);
    const int cnt = __popcll(b);
    int base = 0;
    if (lane == 0 && cnt) base = atomicAdd(wcnt, cnt);
    base = __shfl(base, 0);
    if (flagv) {
      const int pos = base + __popcll(b & ((1ull << lane) - 1));
      if (pos < wlcap) wlist[pos] = pblk + tid;
    }
  }
  __syncthreads();

  // ---- epilogue: q gather/store + loss via x-hat = hi+lo (err ~1e-9 in loss)
  float ls = 0.f;
#pragma unroll
  for (int rt = 0; rt < 4; ++rt) {
    const int lp = p0 + rt * 16 + l15;
    const int bk = bkbuf[lp];
    const float* ep = emb + bk * DIM + side * 32 + d0;
    const f32x4 q0 = *(const f32x4*)ep;                     // L2-hot gather
    const f32x4 q1 = *(const f32x4*)(ep + 4);
    float* op = out + (size_t)n * IMG + (size_t)(side * 32 + d0) * HW + hwb + lp;
    const s8v vh = ah[rt][side], vl = al[rt][side];
#pragma unroll
    for (int j = 0; j < 8; ++j) {
      const float q = (j < 4) ? q0[j] : q1[j - 4];
      op[j * HW] = q;
      const float xv = bf2f(vh[j]) + bf2f(vl[j]);
      const float dd = q - xv;
      ls = fmaf(dd, dd, ls);
    }
  }
  double dls = (double)ls;
#pragma unroll
  for (int o = 32; o; o >>= 1) dls += __shfl_down(dls, o);
  if (lane == 0) red[w] = dls;
  __syncthreads();
  if (tid == 0) {
    double t = 0.0;
#pragma unroll
    for (int q = 0; q < 8; ++q) t += red[q];
    partial[blockIdx.x] = t;
  }
}

// K3: exact fp32 rerank; one block (512 thr = codes) per worklist pixel.
__launch_bounds__(512)
__global__ void vq_fix(const float* __restrict__ in, const float* __restrict__ emb,
                       char* __restrict__ ws, float* __restrict__ out, int wlcap) {
  const float* se = (const float*)(ws + WS_SE);
  const float* et = (const float*)(ws + WS_ET);
  const int* wlist = (const int*)(ws + WS_WL);
  double* partial = (double*)(ws + WS_PART);
  __shared__ float xs[DIM];
  __shared__ float pd[8];
  __shared__ int   pkk[8];
  __shared__ int   sbk;

  const int tid = threadIdx.x;          // == code id
  const int lane = tid & 63, w = tid >> 6;
  int M = *(const int*)(ws + WS_CNT);
  if (M > wlcap) M = wlcap;

  for (int i = blockIdx.x; i < M; i += gridDim.x) {
    const int p = wlist[i];
    const int n = p >> 12, hw = p & 4095;
    if (tid < DIM)
      xs[tid] = in[(size_t)n * IMG + (size_t)tid * HW + hw];  // exact x
    __syncthreads();

    float sx = 0.f, a = 0.f;
#pragma unroll 8
    for (int j = 0; j < DIM; ++j) {     // proven j-ascending chains
      const float xj = xs[j];
      sx = fmaf(xj, xj, sx);
      a  = fmaf(xj, et[j * NUM_K + tid], a);   // coalesced across tid
    }
    float bd = (sx + se[tid]) - 2.f * a;
    int bki = tid;
#pragma unroll
    for (int s = 1; s < 64; s <<= 1) {  // in-wave lex-min (d, k)
      const float od = __shfl_xor(bd, s);
      const int   oi = __shfl_xor(bki, s);
      const bool t = (od < bd) || (od == bd && oi < bki);
      bd = t ? od : bd; bki = t ? oi : bki;
    }
    if (lane == 0) { pd[w] = bd; pkk[w] = bki; }
    __syncthreads();
    if (tid == 0) {
      float fb = pd[0]; int fk = pkk[0];
#pragma unroll
      for (int q = 1; q < 8; ++q)
        if (pd[q] < fb) { fb = pd[q]; fk = pkk[q]; }        // ascending k
      sbk = fk;
    }
    __syncthreads();
    const int bkn = sbk;
    const int oldk = (int)out[IDX_OFF + p];
    if (bkn != oldk && tid < DIM) {
      const float xj = xs[tid];
      const float qn = emb[bkn  * DIM + tid];
      const float qo = emb[oldk * DIM + tid];
      out[(size_t)n * IMG + (size_t)tid * HW + hw] = qn;
      const float dl = (qn - xj) * (qn - xj) - (qo - xj) * (qo - xj);
      double dd = (double)dl;
#pragma unroll
      for (int o = 32; o; o >>= 1) dd += __shfl_down(dd, o);
      if (tid == 0) {
        atomicAdd(&partial[0], dd);
        out[IDX_OFF + p] = (float)bkn;
      }
    }
    __syncthreads();
  }
}

// K4: finalize loss
__global__ void vq_loss(const double* __restrict__ partial, float* __restrict__ out) {
  __shared__ double r2[4];
  const int tid = threadIdx.x;
  double s = partial[tid] + partial[tid + 256];
#pragma unroll
  for (int o = 32; o; o >>= 1) s += __shfl_down(s, o);
  if ((tid & 63) == 0) r2[tid >> 6] = s;
  __syncthreads();
  if (tid == 0) {
    const double t = r2[0] + r2[1] + r2[2] + r2[3];
    out[LOSS_OFF] = (float)(0.25 * t / (double)OUT_Q);
  }
}

extern "C" void kernel_launch(void* const* d_in, const int* in_sizes, int n_in,
                              void* d_out, int out_size, void* d_ws, size_t ws_size,
                              hipStream_t stream) {
  (void)in_sizes; (void)n_in; (void)out_size;
  const float* in  = (const float*)d_in[0];
  const float* emb = (const float*)d_in[1];
  float* out = (float*)d_out;
  char* ws = (char*)d_ws;
  size_t avail = ws_size > WS_WL ? ws_size - WS_WL : 0;
  int wlcap = (int)(avail / 4 < 131072 ? avail / 4 : 131072);
  vq_prep<<<8,    64,  0, stream>>>(emb, ws);
  vq_main<<<512,  512, 0, stream>>>(in, emb, ws, out, wlcap);
  vq_fix <<<2048, 512, 0, stream>>>(in, emb, ws, out, wlcap);
  vq_loss<<<1,    256, 0, stream>>>((const double*)(ws + WS_PART), out);
}

// Round 10
// 182.728 us; speedup vs baseline: 1.0492x; 1.0492x over previous
//
#include <hip/hip_runtime.h>
#include <math.h>

#define NUM_K 512
#define DIM   64
#define HW    4096
#define IMG   (DIM * HW)
#define OUT_Q 8388608
#define LOSS_OFF OUT_Q
#define IDX_OFF (OUT_Q + 1)
#define DELTA 8e-5f
#define NBLK  1024   // vq_main blocks (128 pixels each)

// ws layout (bytes)
#define WS_EH   0        // bf16 hi codebook [512*64] = 64KB
#define WS_EL   65536    // bf16 lo codebook = 64KB
#define WS_SE   131072   // ||e||^2 f32 [512] = 2KB
#define WS_CNT  133120   // worklist counter
#define WS_PART 133376   // loss partials double[1024] = 8KB
#define WS_ET   141568   // transposed codebook f32 [64][512] = 128KB
#define WS_WL   272640   // worklist pixel ids

typedef float f32x4 __attribute__((ext_vector_type(4)));
typedef short s8v   __attribute__((ext_vector_type(8)));

__device__ inline short f2bf(float f) {  // RNE f32->bf16
  unsigned u = __float_as_uint(f);
  return (short)((u + 0x7FFF + ((u >> 16) & 1)) >> 16);
}
__device__ inline float bf2f(short s) {
  return __uint_as_float(((unsigned)(unsigned short)s) << 16);
}

// K1: 8 blocks x 64 thr; LDS-staged coalesced reads; per-code sequential chains
__global__ void vq_prep(const float* __restrict__ emb, char* __restrict__ ws) {
  short* eh = (short*)(ws + WS_EH);
  short* el = (short*)(ws + WS_EL);
  float* se = (float*)(ws + WS_SE);
  float* et = (float*)(ws + WS_ET);
  __shared__ float ebuf[64][65];
  const int tid = threadIdx.x;        // 0..63
  const int kb  = blockIdx.x * 64;
  if (blockIdx.x == 0 && tid == 0) *(int*)(ws + WS_CNT) = 0;
#pragma unroll
  for (int i = 0; i < 64; ++i)        // coalesced
    ebuf[i][tid] = emb[(size_t)(kb + i) * DIM + tid];
  __syncthreads();
  const int k = kb + tid;
  float s = 0.f;
#pragma unroll
  for (int j = 0; j < DIM; ++j) {     // j-ascending sequential (proven chain)
    const float v = ebuf[tid][j];     // pad 65 -> conflict-free
    s = fmaf(v, v, s);
    const short h = f2bf(v);
    eh[k * DIM + j] = h;
    el[k * DIM + j] = f2bf(v - bf2f(h));
    et[j * NUM_K + k] = v;            // coalesced across tid
  }
  se[k] = s;
}

// K2: 256 thr / 4 waves; each wave = 32 pixels (2 row-tiles) x ALL 512 codes.
// Round-8 structure (proven, VGPR 96, no spill) at half the per-block pixels
// -> grid 1024 -> 4 blocks/CU -> 4 waves/SIMD. x-hat epilogue (no x re-read).
__launch_bounds__(256, 4)
__global__ void vq_main(const float* __restrict__ in, const float* __restrict__ emb,
                        char* __restrict__ ws, float* __restrict__ out, int wlcap) {
  const short* eh = (const short*)(ws + WS_EH);
  const short* el = (const short*)(ws + WS_EL);
  const float* se = (const float*)(ws + WS_SE);
  int* wcnt  = (int*)(ws + WS_CNT);
  int* wlist = (int*)(ws + WS_WL);
  double* partial = (double*)(ws + WS_PART);
  __shared__ int bkbuf[128];
  __shared__ unsigned char flg[128];
  __shared__ double red[4];

  const int tid  = threadIdx.x;
  const int lane = tid & 63, w = tid >> 6;   // w 0..3
  const int l15 = lane & 15, lh = lane >> 4;
  const int d0 = lh * 8;
  const int pblk = blockIdx.x * 128;          // 128 contiguous pixels/block
  const int n = pblk >> 12;                   // uniform (128 | 4096)
  const int hwb = pblk & 4095;
  const int p0 = w * 32;                      // wave's 32-pixel slice

  // ---- A-fragments: x[p0+rt*16+l15][h*32+d0+j] as bf16 hi/lo ----
  s8v ah[2][2], al[2][2];
#pragma unroll
  for (int rt = 0; rt < 2; ++rt) {
    const float* xp = in + (size_t)n * IMG + hwb + (p0 + rt * 16 + l15);
#pragma unroll
    for (int h = 0; h < 2; ++h) {
      s8v vh, vl;
#pragma unroll
      for (int j = 0; j < 8; ++j) {
        const float xv = xp[(h * 32 + d0 + j) * HW];
        const short hi = f2bf(xv);
        vh[j] = hi;
        vl[j] = f2bf(xv - bf2f(hi));
      }
      ah[rt][h] = vh; al[rt][h] = vl;
    }
  }

  // ---- 32 code-tiles of 16; packed (value|code) min1/min2 tracking ----
  float m1[2][4], m2[2][4];
#pragma unroll
  for (int rt = 0; rt < 2; ++rt)
#pragma unroll
    for (int r = 0; r < 4; ++r) { m1[rt][r] = INFINITY; m2[rt][r] = INFINITY; }

  for (int ct = 0; ct < 32; ++ct) {
    const int c = ct * 16 + l15;               // this lane's code column
    const s8v beh0 = *(const s8v*)(eh + c * DIM + d0);          // 2KB contig
    const s8v beh1 = *(const s8v*)(eh + c * DIM + 32 + d0);
    const s8v bel0 = *(const s8v*)(el + c * DIM + d0);
    const s8v bel1 = *(const s8v*)(el + c * DIM + 32 + d0);
    const float sec = se[c];
#pragma unroll
    for (int rt = 0; rt < 2; ++rt) {
      f32x4 acc = {0.f, 0.f, 0.f, 0.f};
      acc = __builtin_amdgcn_mfma_f32_16x16x32_bf16(ah[rt][0], beh0, acc, 0, 0, 0);
      acc = __builtin_amdgcn_mfma_f32_16x16x32_bf16(ah[rt][1], beh1, acc, 0, 0, 0);
      acc = __builtin_amdgcn_mfma_f32_16x16x32_bf16(al[rt][0], beh0, acc, 0, 0, 0);
      acc = __builtin_amdgcn_mfma_f32_16x16x32_bf16(al[rt][1], beh1, acc, 0, 0, 0);
      acc = __builtin_amdgcn_mfma_f32_16x16x32_bf16(ah[rt][0], bel0, acc, 0, 0, 0);
      acc = __builtin_amdgcn_mfma_f32_16x16x32_bf16(ah[rt][1], bel1, acc, 0, 0, 0);
#pragma unroll
      for (int r = 0; r < 4; ++r) {
        const float cv = fmaf(-2.f, acc[r], sec);               // se - 2*dot
        const float pk = __int_as_float((__float_as_int(cv) & 0xFFFFFE00) | c);
        m2[rt][r] = fminf(m2[rt][r], fmaxf(m1[rt][r], pk));
        m1[rt][r] = fminf(m1[rt][r], pk);
      }
    }
  }

  // ---- reduce across 16 code-column lanes ----
#pragma unroll
  for (int s = 1; s < 16; s <<= 1) {
#pragma unroll
    for (int rt = 0; rt < 2; ++rt)
#pragma unroll
      for (int r = 0; r < 4; ++r) {
        const float o1 = __shfl_xor(m1[rt][r], s);
        const float o2 = __shfl_xor(m2[rt][r], s);
        const float hi = fmaxf(m1[rt][r], o1);
        m1[rt][r] = fminf(m1[rt][r], o1);
        m2[rt][r] = fminf(fminf(m2[rt][r], o2), hi);
      }
  }
  if (l15 == 0) {
#pragma unroll
    for (int rt = 0; rt < 2; ++rt)
#pragma unroll
      for (int r = 0; r < 4; ++r) {
        const int lp = p0 + rt * 16 + lh * 4 + r;               // C-row pixel
        bkbuf[lp] = __float_as_int(m1[rt][r]) & 511;
        flg[lp] = (m2[rt][r] - m1[rt][r] <= DELTA) ? 1 : 0;
      }
  }
  __syncthreads();

  // ---- idx write + flag compaction (first 2 waves, 1 pixel/thread) ----
  if (tid < 128) {
    const int bk = bkbuf[tid];
    out[IDX_OFF + pblk + tid] = (float)bk;                      // coalesced
    const int f = flg[tid];
    const unsigned long long b = __ballot(f);
    const int cnt = __popcll(b);
    int base = 0;
    if (lane == 0 && cnt) base = atomicAdd(wcnt, cnt);
    base = __shfl(base, 0);
    if (f) {
      const int pos = base + __popcll(b & ((1ull << lane) - 1));
      if (pos < wlcap) wlist[pos] = pblk + tid;
    }
  }
  __syncthreads();

  // ---- epilogue: q gather/store + loss via x-hat = hi+lo ----
  float ls = 0.f;
#pragma unroll
  for (int rt = 0; rt < 2; ++rt) {
    const int lp = p0 + rt * 16 + l15;
    const int bk = bkbuf[lp];
#pragma unroll
    for (int h = 0; h < 2; ++h) {
      const float* ep = emb + bk * DIM + h * 32 + d0;
      const f32x4 q0 = *(const f32x4*)ep;                       // L2-hot gather
      const f32x4 q1 = *(const f32x4*)(ep + 4);
      float* op = out + (size_t)n * IMG + (size_t)(h * 32 + d0) * HW + hwb + lp;
      const s8v vh = ah[rt][h], vl = al[rt][h];
#pragma unroll
      for (int j = 0; j < 8; ++j) {
        const float q = (j < 4) ? q0[j] : q1[j - 4];
        op[j * HW] = q;
        const float xv = bf2f(vh[j]) + bf2f(vl[j]);
        const float dd = q - xv;
        ls = fmaf(dd, dd, ls);
      }
    }
  }
  double dls = (double)ls;
#pragma unroll
  for (int o = 32; o; o >>= 1) dls += __shfl_down(dls, o);
  if (lane == 0) red[w] = dls;
  __syncthreads();
  if (tid == 0) partial[blockIdx.x] = red[0] + red[1] + red[2] + red[3];
}

// K3: exact fp32 rerank; one block (512 thr = codes) per worklist pixel.
__launch_bounds__(512)
__global__ void vq_fix(const float* __restrict__ in, const float* __restrict__ emb,
                       char* __restrict__ ws, float* __restrict__ out, int wlcap) {
  const float* se = (const float*)(ws + WS_SE);
  const float* et = (const float*)(ws + WS_ET);
  const int* wlist = (const int*)(ws + WS_WL);
  double* partial = (double*)(ws + WS_PART);
  __shared__ float xs[DIM];
  __shared__ float pd[8];
  __shared__ int   pkk[8];
  __shared__ int   sbk;

  const int tid = threadIdx.x;          // == code id
  const int lane = tid & 63, w = tid >> 6;
  int M = *(const int*)(ws + WS_CNT);
  if (M > wlcap) M = wlcap;

  for (int i = blockIdx.x; i < M; i += gridDim.x) {
    const int p = wlist[i];
    const int n = p >> 12, hw = p & 4095;
    if (tid < DIM)
      xs[tid] = in[(size_t)n * IMG + (size_t)tid * HW + hw];  // exact x
    __syncthreads();

    float sx = 0.f, a = 0.f;
#pragma unroll 8
    for (int j = 0; j < DIM; ++j) {     // proven j-ascending chains
      const float xj = xs[j];
      sx = fmaf(xj, xj, sx);
      a  = fmaf(xj, et[j * NUM_K + tid], a);   // coalesced across tid
    }
    float bd = (sx + se[tid]) - 2.f * a;
    int bki = tid;
#pragma unroll
    for (int s = 1; s < 64; s <<= 1) {  // in-wave lex-min (d, k)
      const float od = __shfl_xor(bd, s);
      const int   oi = __shfl_xor(bki, s);
      const bool t = (od < bd) || (od == bd && oi < bki);
      bd = t ? od : bd; bki = t ? oi : bki;
    }
    if (lane == 0) { pd[w] = bd; pkk[w] = bki; }
    __syncthreads();
    if (tid == 0) {
      float fb = pd[0]; int fk = pkk[0];
#pragma unroll
      for (int q = 1; q < 8; ++q)
        if (pd[q] < fb) { fb = pd[q]; fk = pkk[q]; }          // ascending k
      sbk = fk;
    }
    __syncthreads();
    const int bkn = sbk;
    const int oldk = (int)out[IDX_OFF + p];
    if (bkn != oldk && tid < DIM) {
      const float xj = xs[tid];
      const float qn = emb[bkn  * DIM + tid];
      const float qo = emb[oldk * DIM + tid];
      out[(size_t)n * IMG + (size_t)tid * HW + hw] = qn;
      const float dl = (qn - xj) * (qn - xj) - (qo - xj) * (qo - xj);
      double dd = (double)dl;
#pragma unroll
      for (int o = 32; o; o >>= 1) dd += __shfl_down(dd, o);
      if (tid == 0) {
        atomicAdd(&partial[0], dd);
        out[IDX_OFF + p] = (float)bkn;
      }
    }
    __syncthreads();
  }
}

// K4: finalize loss (1024 partials)
__global__ void vq_loss(const double* __restrict__ partial, float* __restrict__ out) {
  __shared__ double r2[4];
  const int tid = threadIdx.x;
  double s = partial[tid] + partial[tid + 256] + partial[tid + 512] + partial[tid + 768];
#pragma unroll
  for (int o = 32; o; o >>= 1) s += __shfl_down(s, o);
  if ((tid & 63) == 0) r2[tid >> 6] = s;
  __syncthreads();
  if (tid == 0) {
    const double t = r2[0] + r2[1] + r2[2] + r2[3];
    out[LOSS_OFF] = (float)(0.25 * t / (double)OUT_Q);
  }
}

extern "C" void kernel_launch(void* const* d_in, const int* in_sizes, int n_in,
                              void* d_out, int out_size, void* d_ws, size_t ws_size,
                              hipStream_t stream) {
  (void)in_sizes; (void)n_in; (void)out_size;
  const float* in  = (const float*)d_in[0];
  const float* emb = (const float*)d_in[1];
  float* out = (float*)d_out;
  char* ws = (char*)d_ws;
  size_t avail = ws_size > WS_WL ? ws_size - WS_WL : 0;
  int wlcap = (int)(avail / 4 < 131072 ? avail / 4 : 131072);
  vq_prep<<<8,    64,  0, stream>>>(emb, ws);
  vq_main<<<NBLK, 256, 0, stream>>>(in, emb, ws, out, wlcap);
  vq_fix <<<512,  512, 0, stream>>>(in, emb, ws, out, wlcap);
  vq_loss<<<1,    256, 0, stream>>>((const double*)(ws + WS_PART), out);
}